// Round 8
// baseline (208.304 us; speedup 1.0000x reference)
//
#include <hip/hip_runtime.h>
#include <cstdint>
#include <cstddef>

#define BATCH   4
#define SEQ     4096
#define HIDDEN  4096
#define RANK    512
#define OUTF    4096
#define SROWS   4097              // seq+1
#define MROWS   (BATCH * SROWS)   // 16388

typedef int v4i __attribute__((ext_vector_type(4)));

// ---------------------------------------------------------------------------
// Kernel 1: new_latent[b][r] = dot(new_x[b,0,:], B_weight[r,:])
// ---------------------------------------------------------------------------
__global__ void k_new_latent(const float* __restrict__ newx,
                             const float* __restrict__ Bw,
                             float* __restrict__ out_latent) {
    int wave = threadIdx.x >> 6;
    int lane = threadIdx.x & 63;
    int pair = blockIdx.x * 4 + wave;   // 0..2047
    int b = pair >> 9;
    int r = pair & 511;
    const float4* x4 = (const float4*)(newx + (size_t)b * HIDDEN);
    const float4* w4 = (const float4*)(Bw + (size_t)r * HIDDEN);
    float sum = 0.f;
#pragma unroll
    for (int j = 0; j < 16; ++j) {
        float4 xv = x4[lane + 64 * j];
        float4 wv = w4[lane + 64 * j];
        sum += xv.x * wv.x + xv.y * wv.y + xv.z * wv.z + xv.w * wv.w;
    }
#pragma unroll
    for (int off = 32; off >= 1; off >>= 1)
        sum += __shfl_xor(sum, off, 64);
    if (lane == 0) {
        out_latent[(size_t)(b * SROWS + SEQ) * RANK + r] = sum;
    }
}

// ---------------------------------------------------------------------------
// Kernel 2: per-row int8 quant (rank=512) + copy cached rows to output.
// ---------------------------------------------------------------------------
__global__ void k_quant(const float* __restrict__ cached,
                        float* __restrict__ out_latent,
                        int8_t* __restrict__ Qq,
                        float* __restrict__ scales) {
    int m = blockIdx.x * 4 + (threadIdx.x >> 6);   // 0..16387
    int lane = threadIdx.x & 63;
    int b = m / SROWS;
    int s = m - b * SROWS;
    const float* src = (s < SEQ) ? (cached + ((size_t)b * SEQ + s) * RANK)
                                 : (out_latent + (size_t)m * RANK);
    float4 v0 = ((const float4*)src)[lane];
    float4 v1 = ((const float4*)src)[64 + lane];
    float am = fmaxf(fmaxf(fmaxf(fabsf(v0.x), fabsf(v0.y)),
                           fmaxf(fabsf(v0.z), fabsf(v0.w))),
                     fmaxf(fmaxf(fabsf(v1.x), fabsf(v1.y)),
                           fmaxf(fabsf(v1.z), fabsf(v1.w))));
#pragma unroll
    for (int off = 32; off >= 1; off >>= 1)
        am = fmaxf(am, __shfl_xor(am, off, 64));
    am = fmaxf(am, 1e-8f);
    float scale = am / 127.0f;

    auto qp = [&](float x) -> uint32_t {
        float r = rintf(x / scale);          // round-half-even, matches jnp.round
        r = fminf(fmaxf(r, -128.0f), 127.0f);
        return (uint32_t)(uint8_t)(int8_t)(int)r;
    };
    uint32_t p0 = qp(v0.x) | (qp(v0.y) << 8) | (qp(v0.z) << 16) | (qp(v0.w) << 24);
    uint32_t p1 = qp(v1.x) | (qp(v1.y) << 8) | (qp(v1.z) << 16) | (qp(v1.w) << 24);
    uint32_t* qrow = (uint32_t*)(Qq + (size_t)m * RANK);
    qrow[lane] = p0;
    qrow[64 + lane] = p1;
    if (s < SEQ) {
        float4* dst = (float4*)(out_latent + (size_t)m * RANK);
        dst[lane] = v0;
        dst[64 + lane] = v1;
    }
    if (lane == 0) scales[m] = scale;
}

// ---------------------------------------------------------------------------
// Kernel 3: pack A_int8 (int32 storage, 4096x512) -> int8 bytes.
// ---------------------------------------------------------------------------
__global__ void k_packA(const int* __restrict__ Ai, uint8_t* __restrict__ Ap) {
    int idx = blockIdx.x * blockDim.x + threadIdx.x;
    int4 v = ((const int4*)Ai)[idx];
    uint32_t p = (uint32_t)(v.x & 0xff) | ((uint32_t)(v.y & 0xff) << 8) |
                 ((uint32_t)(v.z & 0xff) << 16) | ((uint32_t)(v.w & 0xff) << 24);
    ((uint32_t*)Ap)[idx] = p;
}

// ---------------------------------------------------------------------------
// Kernel 4: int8 GEMM + dequant — DIRECT GLOBAL->REGISTER, zero LDS,
// zero barriers. Both operands are L2/L3-resident (Ap 2 MB, Qq 8.4 MB,
// Q-panels shared across the 32 tn-blocks of a tm via the XCD swizzle).
// Each wave owns a 64x64 sub-tile: per K-step (BK=64) loads its 8 fragments
// (4 aF + 4 bF, global_load_dwordx4: 16 rows x 16 B each) straight into
// VGPRs with depth-1 prefetch, then 16 mfma_i32_16x16x64_i8.
// No stage->vmcnt->barrier critical path (the R3..R6-proven stall).
// ---------------------------------------------------------------------------
#define BM 128
#define BN 128
#define BK 64
#define NT_N (OUTF / BN)   // 32
#define NKT  (RANK / BK)   // 8

__launch_bounds__(256, 3)
__global__ void k_gemm(const int8_t* __restrict__ Qq,
                       const int8_t* __restrict__ Ap,
                       const float* __restrict__ scales,
                       const float* __restrict__ Ascale,
                       float* __restrict__ out,
                       int M) {
    // XCD-bijective blockIdx swizzle (gridDim.x = 4128, % 8 == 0): each XCD
    // gets a contiguous swz stripe (tn-minor) -> co-XCD blocks share Q-panel.
    int per = gridDim.x >> 3;
    int bid = blockIdx.x;
    int swz = (bid & 7) * per + (bid >> 3);
    int tn = swz & (NT_N - 1);
    int tm = swz / NT_N;

    int tid = threadIdx.x;
    int lane = tid & 63;
    int wave = tid >> 6;
    int wr = wave >> 1, wc = wave & 1;
    int m0 = tm * BM;
    int n0 = tn * BN;

    int g = lane >> 4;        // K-quarter (16 B chunk within the 64 B K-step)
    int rl = lane & 15;       // row within fragment

    // Per-fragment base pointers (K-step offsets are compile-time +64*kt).
    const int8_t* ap[4];
    const int8_t* bp[4];
#pragma unroll
    for (int mi = 0; mi < 4; ++mi) {
        int row = m0 + wr * 64 + mi * 16 + rl;
        if (row >= M) row = M - 1;                 // tail clamp (discarded later)
        ap[mi] = Qq + (size_t)row * RANK + g * 16;
    }
#pragma unroll
    for (int ni = 0; ni < 4; ++ni) {
        int row = n0 + wc * 64 + ni * 16 + rl;
        bp[ni] = Ap + (size_t)row * RANK + g * 16;
    }

    v4i aF[2][4], bF[2][4];
#pragma unroll
    for (int x = 0; x < 4; ++x) {
        aF[0][x] = *(const v4i*)(ap[x]);
        bF[0][x] = *(const v4i*)(bp[x]);
    }

    v4i acc[4][4] = {};
#pragma unroll
    for (int kt = 0; kt < NKT; ++kt) {
        const int cur = kt & 1;
        if (kt < NKT - 1) {
            const int off = (kt + 1) * BK;
#pragma unroll
            for (int x = 0; x < 4; ++x) {
                aF[cur ^ 1][x] = *(const v4i*)(ap[x] + off);
                bF[cur ^ 1][x] = *(const v4i*)(bp[x] + off);
            }
        }
#pragma unroll
        for (int mi = 0; mi < 4; ++mi)
#pragma unroll
            for (int ni = 0; ni < 4; ++ni)
                acc[mi][ni] = __builtin_amdgcn_mfma_i32_16x16x64_i8(
                    aF[cur][mi], bF[cur][ni], acc[mi][ni], 0, 0, 0);
    }

    // Epilogue: dequant + store. C/D: col = lane&15, row = (lane>>4)*4+r.
    int gq = lane >> 4;
    int cn = lane & 15;
#pragma unroll
    for (int mi = 0; mi < 4; ++mi) {
        int mbase = m0 + wr * 64 + mi * 16 + gq * 4;
        float sm[4];
#pragma unroll
        for (int r = 0; r < 4; ++r) {
            int mm = mbase + r;
            sm[r] = (mm < M) ? scales[mm] : 0.f;
        }
#pragma unroll
        for (int ni = 0; ni < 4; ++ni) {
            int n = n0 + wc * 64 + ni * 16 + cn;
            float asc = Ascale[n];
#pragma unroll
            for (int r = 0; r < 4; ++r) {
                int mm = mbase + r;
                if (mm < M)
                    out[(size_t)mm * OUTF + n] = (float)acc[mi][ni][r] * sm[r] * asc;
            }
        }
    }
}

// ---------------------------------------------------------------------------
extern "C" void kernel_launch(void* const* d_in, const int* in_sizes, int n_in,
                              void* d_out, int out_size, void* d_ws, size_t ws_size,
                              hipStream_t stream) {
    const float* new_x  = (const float*)d_in[0];
    const float* cached = (const float*)d_in[1];
    const float* Bw     = (const float*)d_in[2];
    const int*   Ai     = (const int*)d_in[3];
    const float* Ascale = (const float*)d_in[4];

    float* out = (float*)d_out;
    float* out_latent = out + (size_t)MROWS * OUTF;

    const size_t Q_BYTES = (size_t)MROWS * RANK;
    const size_t S_BYTES = (size_t)MROWS * sizeof(float);
    int8_t*  Qq     = (int8_t*)d_ws;
    float*   scales = (float*)((char*)d_ws + Q_BYTES);
    int8_t*  Ap     = (int8_t*)((char*)d_ws + Q_BYTES + S_BYTES);

    k_new_latent<<<512, 256, 0, stream>>>(new_x, Bw, out_latent);
    k_quant<<<SROWS, 256, 0, stream>>>(cached, out_latent, Qq, scales);
    k_packA<<<(OUTF * RANK / 4) / 256, 256, 0, stream>>>(Ai, (uint8_t*)Ap);
    int nt_m = (MROWS + BM - 1) / BM;   // 129
    k_gemm<<<nt_m * NT_N, 256, 0, stream>>>(Qq, Ap, scales, Ascale, out, MROWS);
}

// Round 9
// 134.231 us; speedup vs baseline: 1.5518x; 1.5518x over previous
//
#include <hip/hip_runtime.h>
#include <cstdint>
#include <cstddef>

#define BATCH   4
#define SEQ     4096
#define HIDDEN  4096
#define RANK    512
#define OUTF    4096
#define SROWS   4097              // seq+1
#define MROWS   (BATCH * SROWS)   // 16388

typedef int v4i __attribute__((ext_vector_type(4)));

#define AS1 __attribute__((address_space(1)))
#define AS3 __attribute__((address_space(3)))

// ---------------------------------------------------------------------------
// Kernel 1: new_latent[b][r] = dot(new_x[b,0,:], B_weight[r,:])
// ---------------------------------------------------------------------------
__global__ void k_new_latent(const float* __restrict__ newx,
                             const float* __restrict__ Bw,
                             float* __restrict__ out_latent) {
    int wave = threadIdx.x >> 6;
    int lane = threadIdx.x & 63;
    int pair = blockIdx.x * 4 + wave;   // 0..2047
    int b = pair >> 9;
    int r = pair & 511;
    const float4* x4 = (const float4*)(newx + (size_t)b * HIDDEN);
    const float4* w4 = (const float4*)(Bw + (size_t)r * HIDDEN);
    float sum = 0.f;
#pragma unroll
    for (int j = 0; j < 16; ++j) {
        float4 xv = x4[lane + 64 * j];
        float4 wv = w4[lane + 64 * j];
        sum += xv.x * wv.x + xv.y * wv.y + xv.z * wv.z + xv.w * wv.w;
    }
#pragma unroll
    for (int off = 32; off >= 1; off >>= 1)
        sum += __shfl_xor(sum, off, 64);
    if (lane == 0) {
        out_latent[(size_t)(b * SROWS + SEQ) * RANK + r] = sum;
    }
}

// ---------------------------------------------------------------------------
// Kernel 2: per-row int8 quant (rank=512) + copy cached rows to output.
// ---------------------------------------------------------------------------
__global__ void k_quant(const float* __restrict__ cached,
                        float* __restrict__ out_latent,
                        int8_t* __restrict__ Qq,
                        float* __restrict__ scales) {
    int m = blockIdx.x * 4 + (threadIdx.x >> 6);   // 0..16387
    int lane = threadIdx.x & 63;
    int b = m / SROWS;
    int s = m - b * SROWS;
    const float* src = (s < SEQ) ? (cached + ((size_t)b * SEQ + s) * RANK)
                                 : (out_latent + (size_t)m * RANK);
    float4 v0 = ((const float4*)src)[lane];
    float4 v1 = ((const float4*)src)[64 + lane];
    float am = fmaxf(fmaxf(fmaxf(fabsf(v0.x), fabsf(v0.y)),
                           fmaxf(fabsf(v0.z), fabsf(v0.w))),
                     fmaxf(fmaxf(fabsf(v1.x), fabsf(v1.y)),
                           fmaxf(fabsf(v1.z), fabsf(v1.w))));
#pragma unroll
    for (int off = 32; off >= 1; off >>= 1)
        am = fmaxf(am, __shfl_xor(am, off, 64));
    am = fmaxf(am, 1e-8f);
    float scale = am / 127.0f;

    auto qp = [&](float x) -> uint32_t {
        float r = rintf(x / scale);          // round-half-even, matches jnp.round
        r = fminf(fmaxf(r, -128.0f), 127.0f);
        return (uint32_t)(uint8_t)(int8_t)(int)r;
    };
    uint32_t p0 = qp(v0.x) | (qp(v0.y) << 8) | (qp(v0.z) << 16) | (qp(v0.w) << 24);
    uint32_t p1 = qp(v1.x) | (qp(v1.y) << 8) | (qp(v1.z) << 16) | (qp(v1.w) << 24);
    uint32_t* qrow = (uint32_t*)(Qq + (size_t)m * RANK);
    qrow[lane] = p0;
    qrow[64 + lane] = p1;
    if (s < SEQ) {
        float4* dst = (float4*)(out_latent + (size_t)m * RANK);
        dst[lane] = v0;
        dst[64 + lane] = v1;
    }
    if (lane == 0) scales[m] = scale;
}

// ---------------------------------------------------------------------------
// Kernel 3: pack A_int8 (int32 storage, 4096x512) -> int8 bytes.
// ---------------------------------------------------------------------------
__global__ void k_packA(const int* __restrict__ Ai, uint8_t* __restrict__ Ap) {
    int idx = blockIdx.x * blockDim.x + threadIdx.x;
    int4 v = ((const int4*)Ai)[idx];
    uint32_t p = (uint32_t)(v.x & 0xff) | ((uint32_t)(v.y & 0xff) << 8) |
                 ((uint32_t)(v.z & 0xff) << 16) | ((uint32_t)(v.w & 0xff) << 24);
    ((uint32_t*)Ap)[idx] = p;
}

// ---------------------------------------------------------------------------
// Kernel 4: int8 GEMM + dequant — OCCUPANCY-FIRST variant.
// BM=128, BN=64, BK=64, 4 waves (2Mx2N), each wave 64x32 -> acc = 8 v4i
// = 32 VGPR. Dbuf LDS 24 KB. Target 6 blocks/CU (24 waves, 6 independent
// barrier groups) — the only lever that has moved this latency-bound GEMM
// (R4/R7/R8: 1 block/CU -> 138-200us; R3/R6: 4 -> 113us).
// Pair-XOR chunk swizzle (proven-correct R6) + counted vmcnt(3).
// ---------------------------------------------------------------------------
#define BM 128
#define BN 64
#define BK 64
#define NT_N (OUTF / BN)   // 64
#define NKT  (RANK / BK)   // 8

__launch_bounds__(256, 6)
__global__ void k_gemm(const int8_t* __restrict__ Qq,
                       const int8_t* __restrict__ Ap,
                       const float* __restrict__ scales,
                       const float* __restrict__ Ascale,
                       float* __restrict__ out,
                       int M) {
    __shared__ __align__(16) int8_t Qs[2][BM * BK];   // 2 x 8 KiB
    __shared__ __align__(16) int8_t As[2][BN * BK];   // 2 x 4 KiB

    // XCD-bijective blockIdx swizzle (gridDim.x = 8256, % 8 == 0), tn-minor:
    // co-XCD blocks share the Q-panel (64 KB) and A (2 MB) in L2.
    int per = gridDim.x >> 3;
    int bid = blockIdx.x;
    int swz = (bid & 7) * per + (bid >> 3);
    int tn = swz & (NT_N - 1);
    int tm = swz >> 6;          // / NT_N

    int tid = threadIdx.x;
    int lane = tid & 63;
    int wave = tid >> 6;
    int wr = wave >> 1, wc = wave & 1;
    int m0 = tm * BM;
    int n0 = tn * BN;

    // Staging: thread tid -> Q rows R0 = tid>>2 and R0+64 (2 chunks),
    // A row R0 (1 chunk). LDS chunk slot s = tid&3, swizzled global chunk
    // cg = s ^ ((R0>>1)&3). LDS linear: chunk idx at byte idx*16.
    int R0 = tid >> 2;
    int cg = (tid & 3) ^ ((tid >> 3) & 3);
    int grow0 = m0 + R0;       if (grow0 >= M) grow0 = M - 1;
    int grow1 = m0 + R0 + 64;  if (grow1 >= M) grow1 = M - 1;
    const int8_t* q0 = Qq + (size_t)grow0 * RANK + cg * 16;
    const int8_t* q1 = Qq + (size_t)grow1 * RANK + cg * 16;
    const int8_t* a0 = Ap + (size_t)(n0 + R0) * RANK + cg * 16;
    uint32_t wb = (uint32_t)(wave * 1024);   // wave-uniform LDS byte base

#define STAGE(bufi, kt) do {                                                  \
    int off_ = (kt) * BK;                                                     \
    __builtin_amdgcn_global_load_lds((const AS1 uint32_t*)(q0 + off_),        \
        (AS3 uint32_t*)(&Qs[bufi][0] + wb), 16, 0, 0);                        \
    __builtin_amdgcn_global_load_lds((const AS1 uint32_t*)(q1 + off_),        \
        (AS3 uint32_t*)(&Qs[bufi][0] + wb + 4096), 16, 0, 0);                 \
    __builtin_amdgcn_global_load_lds((const AS1 uint32_t*)(a0 + off_),        \
        (AS3 uint32_t*)(&As[bufi][0] + wb), 16, 0, 0);                        \
  } while (0)

    v4i acc[4][2] = {};
    int g = lane >> 4;                 // K-quarter
    int rl = lane & 15;
    int sl = g ^ ((rl >> 1) & 3);      // swizzled LDS chunk slot

    STAGE(0, 0);
#pragma unroll
    for (int kt = 0; kt < NKT; ++kt) {
        int cb = kt & 1;
        if (kt < NKT - 1) {
            STAGE(cb ^ 1, kt + 1);
            asm volatile("s_waitcnt vmcnt(3)" ::: "memory");
        } else {
            asm volatile("s_waitcnt vmcnt(0)" ::: "memory");
        }
        __builtin_amdgcn_s_barrier();   // tile kt fully in LDS

        v4i aF[4], bF[2];
#pragma unroll
        for (int mi = 0; mi < 4; ++mi) {
            int row = wr * 64 + mi * 16 + rl;
            aF[mi] = *(const v4i*)(&Qs[cb][0] + row * BK + sl * 16);
        }
#pragma unroll
        for (int ni = 0; ni < 2; ++ni) {
            int row = wc * 32 + ni * 16 + rl;
            bF[ni] = *(const v4i*)(&As[cb][0] + row * BK + sl * 16);
        }
#pragma unroll
        for (int mi = 0; mi < 4; ++mi)
#pragma unroll
            for (int ni = 0; ni < 2; ++ni)
                acc[mi][ni] = __builtin_amdgcn_mfma_i32_16x16x64_i8(
                    aF[mi], bF[ni], acc[mi][ni], 0, 0, 0);

        __builtin_amdgcn_s_barrier();   // reads done before next overwrite
    }
#undef STAGE

    // Epilogue: dequant + store. C/D: col = lane&15, row = (lane>>4)*4+r.
    int gq = lane >> 4;
    int cn = lane & 15;
#pragma unroll
    for (int mi = 0; mi < 4; ++mi) {
        int mbase = m0 + wr * 64 + mi * 16 + gq * 4;
        float sm[4];
#pragma unroll
        for (int r = 0; r < 4; ++r) {
            int mm = mbase + r;
            sm[r] = (mm < M) ? scales[mm] : 0.f;
        }
#pragma unroll
        for (int ni = 0; ni < 2; ++ni) {
            int n = n0 + wc * 32 + ni * 16 + cn;
            float asc = Ascale[n];
#pragma unroll
            for (int r = 0; r < 4; ++r) {
                int mm = mbase + r;
                if (mm < M)
                    out[(size_t)mm * OUTF + n] = (float)acc[mi][ni][r] * sm[r] * asc;
            }
        }
    }
}

// ---------------------------------------------------------------------------
extern "C" void kernel_launch(void* const* d_in, const int* in_sizes, int n_in,
                              void* d_out, int out_size, void* d_ws, size_t ws_size,
                              hipStream_t stream) {
    const float* new_x  = (const float*)d_in[0];
    const float* cached = (const float*)d_in[1];
    const float* Bw     = (const float*)d_in[2];
    const int*   Ai     = (const int*)d_in[3];
    const float* Ascale = (const float*)d_in[4];

    float* out = (float*)d_out;
    float* out_latent = out + (size_t)MROWS * OUTF;

    const size_t Q_BYTES = (size_t)MROWS * RANK;
    const size_t S_BYTES = (size_t)MROWS * sizeof(float);
    int8_t*  Qq     = (int8_t*)d_ws;
    float*   scales = (float*)((char*)d_ws + Q_BYTES);
    int8_t*  Ap     = (int8_t*)((char*)d_ws + Q_BYTES + S_BYTES);

    k_new_latent<<<512, 256, 0, stream>>>(new_x, Bw, out_latent);
    k_quant<<<SROWS, 256, 0, stream>>>(cached, out_latent, Qq, scales);
    k_packA<<<(OUTF * RANK / 4) / 256, 256, 0, stream>>>(Ai, (uint8_t*)Ap);
    int nt_m = (MROWS + BM - 1) / BM;   // 129
    k_gemm<<<nt_m * NT_N, 256, 0, stream>>>(Qq, Ap, scales, Ascale, out, MROWS);
}